// Round 3
// baseline (55.351 us; speedup 1.0000x reference)
//
#include <hip/hip_runtime.h>
#include <hip/hip_bf16.h>

// Problem: B=N=1024, in_f=1024, OUT_F=32, KD=8
// out[n][0:1024]   = x[n][:]
// M[n][o*8+k]      = sum_f x[n][f] * T[f][o*8+k]        (T flat [1024][256])
// out[n][1024+o]   = sum_{i != n} exp(-sum_k |M[i][o*8+k] - M[n][o*8+k]|)

#define N_ROWS 1024
#define IN_F   1024
#define OUT_C  1056
#define OK     256   // OUT_F*KD
#define KS     16    // K-split factor
#define KC     64    // K-chunk = IN_F/KS
#define APITCH 132   // k-major A tile pitch (8*132 % 32 != 0 would be ideal; 132 chosen for 16B align)

// ---------------- kernel 1: strided copy of x into out ----------------
__global__ __launch_bounds__(256) void copy_x_kernel(
    const float* __restrict__ x, float* __restrict__ out) {
  int n = blockIdx.x;          // 0..1023
  int c = threadIdx.x * 4;     // 256 threads * 4 floats = 1024
  float4 v = *reinterpret_cast<const float4*>(x + (size_t)n * IN_F + c);
  *reinterpret_cast<float4*>(out + (size_t)n * OUT_C + c) = v;
}

// ---------------- kernel 2: fp32 GEMM, 128x128 tile, 8x8/thread, K-split 16 ----
// grid (8 m, 2 n, 16 ks) = 256 blocks, 256 threads. One-shot LDS staging, one barrier.
// A staged k-major (as[k][row]) so inner-loop reads are bank-conflict-free b128.
__global__ __launch_bounds__(256) void gemm8_kernel(
    const float* __restrict__ A,   // x [1024][1024]
    const float* __restrict__ Bm,  // T [1024][256]
    float* __restrict__ part) {    // [KS][1024][256]
  __shared__ float as[KC][APITCH];   // k-major: as[k][row], 33.8 KB
  __shared__ float bs[KC][128];      // row-major: bs[k][col], 32.8 KB
  const int m0 = blockIdx.x * 128;
  const int n0 = blockIdx.y * 128;
  const int k0 = blockIdx.z * KC;
  const int t  = threadIdx.x;

  // stage A: 128 rows x 64 k = 2048 float4, transpose to k-major via 4x ds_write_b32
#pragma unroll
  for (int u = 0; u < 8; ++u) {
    int idx = t + 256 * u;
    int row = idx >> 4, q4 = idx & 15;   // 16 float4 per row
    float4 v = *reinterpret_cast<const float4*>(A + (size_t)(m0 + row) * IN_F + k0 + q4 * 4);
    as[q4 * 4 + 0][row] = v.x;
    as[q4 * 4 + 1][row] = v.y;
    as[q4 * 4 + 2][row] = v.z;
    as[q4 * 4 + 3][row] = v.w;
  }
  // stage B: 64 k x 128 cols = 2048 float4, natural layout
#pragma unroll
  for (int u = 0; u < 8; ++u) {
    int idx = t + 256 * u;
    int row = idx >> 5, c4 = idx & 31;   // 32 float4 per k-row
    *reinterpret_cast<float4*>(&bs[row][c4 * 4]) =
        *reinterpret_cast<const float4*>(Bm + (size_t)(k0 + row) * OK + n0 + c4 * 4);
  }
  __syncthreads();

  const int ty = t >> 4, tx = t & 15;
  // rows: m0 + ty*8 + r (r 0..7); cols: n0 + tx*4 + c (c 0..3) and n0 + 64 + tx*4 + c
  float acc[8][8] = {};   // acc[r][h*4+c]

#pragma unroll 4
  for (int kk = 0; kk < KC; ++kk) {
    float4 a0 = *reinterpret_cast<const float4*>(&as[kk][ty * 8]);
    float4 a1 = *reinterpret_cast<const float4*>(&as[kk][ty * 8 + 4]);
    float4 b0 = *reinterpret_cast<const float4*>(&bs[kk][tx * 4]);
    float4 b1 = *reinterpret_cast<const float4*>(&bs[kk][64 + tx * 4]);
    float ar[8] = {a0.x, a0.y, a0.z, a0.w, a1.x, a1.y, a1.z, a1.w};
    float br[8] = {b0.x, b0.y, b0.z, b0.w, b1.x, b1.y, b1.z, b1.w};
#pragma unroll
    for (int r = 0; r < 8; ++r)
#pragma unroll
      for (int c = 0; c < 8; ++c)
        acc[r][c] = fmaf(ar[r], br[c], acc[r][c]);
  }

  float* dst = part + (size_t)blockIdx.z * (N_ROWS * OK);
#pragma unroll
  for (int r = 0; r < 8; ++r) {
    int row = m0 + ty * 8 + r;
    *reinterpret_cast<float4*>(&dst[(size_t)row * OK + n0 + tx * 4]) =
        make_float4(acc[r][0], acc[r][1], acc[r][2], acc[r][3]);
    *reinterpret_cast<float4*>(&dst[(size_t)row * OK + n0 + 64 + tx * 4]) =
        make_float4(acc[r][4], acc[r][5], acc[r][6], acc[r][7]);
  }
}

// ---------------- kernel 2b: reduce K-split partials ----------------
__global__ __launch_bounds__(256) void reduce_kernel(
    const float* __restrict__ part, float* __restrict__ M) {
  int g = blockIdx.x * 256 + threadIdx.x;         // 65536 float4 groups
  const float4* p = reinterpret_cast<const float4*>(part);
  float4 s = p[g];
#pragma unroll
  for (int sl = 1; sl < KS; ++sl) {
    float4 v = p[g + (size_t)sl * (N_ROWS * OK / 4)];
    s.x += v.x; s.y += v.y; s.z += v.z; s.w += v.w;
  }
  reinterpret_cast<float4*>(M)[g] = s;
}

// ---------------- fallback GEMM (small ws): single-pass ----------------
#define BK 16
__global__ __launch_bounds__(256) void gemm32_kernel(
    const float* __restrict__ A, const float* __restrict__ Bm, float* __restrict__ M) {
  __shared__ float as2[BK][32];
  __shared__ float bs2[BK][32];
  int m0 = blockIdx.x * 32;
  int n0 = blockIdx.y * 32;
  int t  = threadIdx.x;
  int ty = t >> 4, tx = t & 15;
  float c00 = 0.f, c01 = 0.f, c10 = 0.f, c11 = 0.f;
  for (int k0 = 0; k0 < IN_F; k0 += BK) {
    if (t < 128) {
      int row = t >> 2, q = t & 3;
      float4 v = *reinterpret_cast<const float4*>(A + (size_t)(m0 + row) * IN_F + k0 + q * 4);
      as2[q * 4 + 0][row] = v.x; as2[q * 4 + 1][row] = v.y;
      as2[q * 4 + 2][row] = v.z; as2[q * 4 + 3][row] = v.w;
    } else {
      int tt = t - 128;
      int row = tt >> 3, q = tt & 7;
      float4 v = *reinterpret_cast<const float4*>(Bm + (size_t)(k0 + row) * OK + n0 + q * 4);
      *reinterpret_cast<float4*>(&bs2[row][q * 4]) = v;
    }
    __syncthreads();
#pragma unroll
    for (int kk = 0; kk < BK; ++kk) {
      float2 a = *reinterpret_cast<const float2*>(&as2[kk][ty * 2]);
      float2 b = *reinterpret_cast<const float2*>(&bs2[kk][tx * 2]);
      c00 += a.x * b.x; c01 += a.x * b.y;
      c10 += a.y * b.x; c11 += a.y * b.y;
    }
    __syncthreads();
  }
  int r = m0 + ty * 2, c = n0 + tx * 2;
  M[(size_t)r * OK + c]           = c00;
  M[(size_t)r * OK + c + 1]       = c01;
  M[(size_t)(r + 1) * OK + c]     = c10;
  M[(size_t)(r + 1) * OK + c + 1] = c11;
}

// ---------------- kernel 3: pairwise exp(-L1), no LDS staging ----------------
// grid (o: 32, jt: 8) = 256 blocks, 512 threads (8 waves -> 2/SIMD).
// Thread: jl = t&63, wave s = t>>6. Owns j0=jt*128+jl, j1=j0+64 (rows in regs);
// iterates i in [s*128, s*128+128). The i-row load address is wave-uniform ->
// one 32B L2 request per wave per iter; no LDS on the critical path.
__global__ __launch_bounds__(512) void pairwise_kernel(
    const float* __restrict__ M, float* __restrict__ out) {
  __shared__ float red[8][128];

  int o  = blockIdx.x;
  int jt = blockIdx.y;
  int t  = threadIdx.x;
  int jl = t & 63, s = t >> 6;
  int j0 = jt * 128 + jl, j1 = j0 + 64;

  const float* Mo = M + o * 8;
  float4 ra0 = *reinterpret_cast<const float4*>(Mo + (size_t)j0 * OK);
  float4 rb0 = *reinterpret_cast<const float4*>(Mo + (size_t)j0 * OK + 4);
  float4 ra1 = *reinterpret_cast<const float4*>(Mo + (size_t)j1 * OK);
  float4 rb1 = *reinterpret_cast<const float4*>(Mo + (size_t)j1 * OK + 4);

  float acc0 = 0.f, acc1 = 0.f;
  int i0 = s * 128;
#pragma unroll 4
  for (int i = i0; i < i0 + 128; ++i) {
    float4 va = *reinterpret_cast<const float4*>(Mo + (size_t)i * OK);
    float4 vb = *reinterpret_cast<const float4*>(Mo + (size_t)i * OK + 4);
    float d0 = (fabsf(va.x - ra0.x) + fabsf(va.y - ra0.y) + fabsf(va.z - ra0.z)) +
               (fabsf(va.w - ra0.w) + fabsf(vb.x - rb0.x) + fabsf(vb.y - rb0.y)) +
               (fabsf(vb.z - rb0.z) + fabsf(vb.w - rb0.w));
    float d1 = (fabsf(va.x - ra1.x) + fabsf(va.y - ra1.y) + fabsf(va.z - ra1.z)) +
               (fabsf(va.w - ra1.w) + fabsf(vb.x - rb1.x) + fabsf(vb.y - rb1.y)) +
               (fabsf(vb.z - rb1.z) + fabsf(vb.w - rb1.w));
    // exp(-d) < e^-30: total contribution < 1e-10 over 1024 terms -> skip
    if (d0 < 30.f) acc0 += __expf(-d0);
    if (d1 < 30.f) acc1 += __expf(-d1);
  }
  if ((j0 >> 7) == s) acc0 -= 1.0f;   // exact self term exp(0)=1
  if ((j1 >> 7) == s) acc1 -= 1.0f;

  red[s][jl]      = acc0;
  red[s][64 + jl] = acc1;
  __syncthreads();

  if (t < 128) {
    float v = 0.f;
#pragma unroll
    for (int q = 0; q < 8; ++q) v += red[q][t];
    out[(size_t)(jt * 128 + t) * OUT_C + 1024 + o] = v;
  }
}

extern "C" void kernel_launch(void* const* d_in, const int* in_sizes, int n_in,
                              void* d_out, int out_size, void* d_ws, size_t ws_size,
                              hipStream_t stream) {
  const float* x = (const float*)d_in[0];   // [1024][1024]
  const float* T = (const float*)d_in[1];   // [1024][256]
  float* out = (float*)d_out;               // [1024][1056]

  copy_x_kernel<<<dim3(N_ROWS), dim3(256), 0, stream>>>(x, out);

  const size_t mBytes    = (size_t)N_ROWS * OK * sizeof(float);   // 1 MB
  const size_t partBytes = (size_t)KS * mBytes;                   // 16 MB

  if (ws_size >= partBytes + mBytes) {
    float* part = (float*)d_ws;
    float* M    = (float*)((char*)d_ws + partBytes);
    gemm8_kernel<<<dim3(8, 2, KS), dim3(256), 0, stream>>>(x, T, part);
    reduce_kernel<<<dim3(256), dim3(256), 0, stream>>>(part, M);
    pairwise_kernel<<<dim3(32, 8), dim3(512), 0, stream>>>(M, out);
  } else {
    float* M = (float*)d_ws;
    gemm32_kernel<<<dim3(32, 8), dim3(256), 0, stream>>>(x, T, M);
    pairwise_kernel<<<dim3(32, 8), dim3(512), 0, stream>>>(M, out);
  }
}